// Round 1
// baseline (420.879 us; speedup 1.0000x reference)
//
#include <hip/hip_runtime.h>
#include <hip/hip_bf16.h>
#include <stdint.h>

#define B_   4
#define N_   4096
#define HID_ 768
#define H_   12
#define DH_  64
#define NB_  266
#define NBP_ 288          // NB padded to multiple of 32 for MFMA K/N tiling
#define EPS_ 1e-4f

typedef unsigned short u16;
typedef __attribute__((ext_vector_type(8))) short short8;
typedef __attribute__((ext_vector_type(4))) float floatx4;

__device__ __forceinline__ u16 f2b(float f) {
  __hip_bfloat16 h = __float2bfloat16(f);
  return *reinterpret_cast<u16*>(&h);
}
__device__ __forceinline__ float b2f(u16 u) {
  union { unsigned u; float f; } x; x.u = ((unsigned)u) << 16; return x.f;
}
// monotone float<->uint mapping for atomicMax on floats
__device__ __forceinline__ unsigned fmap(float x) {
  unsigned u = __float_as_uint(x);
  return (u & 0x80000000u) ? ~u : (u | 0x80000000u);
}
__device__ __forceinline__ float funmap(unsigned u) {
  unsigned b = (u & 0x80000000u) ? (u & 0x7FFFFFFFu) : ~u;
  return __uint_as_float(b);
}

// ---------------- converts / init ----------------
__global__ void k_convert(const float* __restrict__ src, u16* __restrict__ dst, int n) {
  int i = blockIdx.x * blockDim.x + threadIdx.x;
  int stride = gridDim.x * blockDim.x;
  for (; i < n; i += stride) dst[i] = f2b(src[i]);
}

__global__ void k_prep_proj(const float* __restrict__ proj, u16* __restrict__ dst) {
  int i = blockIdx.x * 256 + threadIdx.x;          // NBP_*DH_ = 18432
  if (i >= NBP_ * DH_) return;
  int j = i / DH_, d = i - j * DH_;
  float v = (j < NB_) ? proj[j * DH_ + d] * 0.35355339059327373f : 0.f;  // fold dn=64^-0.25
  dst[i] = f2b(v);
}

__global__ void k_init(float* __restrict__ zf, unsigned* __restrict__ mbuf, int nf) {
  int i = blockIdx.x * 256 + threadIdx.x;
  if (i < nf) zf[i] = 0.f;
  if (i < B_ * H_) mbuf[i] = 0u;  // 0 < fmap(any real): acts as -inf
}

// ---------------- QKV projection GEMM (bf16 MFMA, 128x128 tile, BK=32) ----------------
__global__ __launch_bounds__(256) void k_qkv(
    const u16* __restrict__ hsb, const u16* __restrict__ wb,
    const float* __restrict__ bq, const float* __restrict__ bk, const float* __restrict__ bv,
    u16* __restrict__ qb, u16* __restrict__ kb, u16* __restrict__ vb) {
  __shared__ u16 At[128][40];   // +8 pad: rows at +20 banks -> 2-way max (free)
  __shared__ u16 Bt[128][40];
  const int bm = blockIdx.x, bn = blockIdx.y;
  const int m0 = bm * 128;
  const int sel = bn / 6;                  // 0:q 1:k 2:v (768/128=6 col-blocks each)
  const int or0 = (bn % 6) * 128;
  const u16* W = wb + (size_t)sel * HID_ * HID_;
  const int t = threadIdx.x, lane = t & 63, wv = t >> 6;
  const int wr = (wv >> 1) * 64, wc = (wv & 1) * 64;
  const int lm = lane & 15, lq = lane >> 4;
  floatx4 acc[4][4];
#pragma unroll
  for (int i = 0; i < 4; i++)
#pragma unroll
    for (int j = 0; j < 4; j++) acc[i][j] = (floatx4){0.f, 0.f, 0.f, 0.f};

  for (int k0 = 0; k0 < HID_; k0 += 32) {
    __syncthreads();
#pragma unroll
    for (int i = 0; i < 2; i++) {
      int c = t + i * 256;
      int r = c >> 2, off = (c & 3) * 8;
      *(uint4*)&At[r][off] = *(const uint4*)(hsb + (size_t)(m0 + r) * HID_ + k0 + off);
      *(uint4*)&Bt[r][off] = *(const uint4*)(W + (size_t)(or0 + r) * HID_ + k0 + off);
    }
    __syncthreads();
    short8 af[4], bfr[4];
#pragma unroll
    for (int mt = 0; mt < 4; mt++) af[mt] = *(const short8*)&At[wr + mt * 16 + lm][lq * 8];
#pragma unroll
    for (int nt = 0; nt < 4; nt++) bfr[nt] = *(const short8*)&Bt[wc + nt * 16 + lm][lq * 8];
#pragma unroll
    for (int mt = 0; mt < 4; mt++)
#pragma unroll
      for (int nt = 0; nt < 4; nt++)
        acc[mt][nt] = __builtin_amdgcn_mfma_f32_16x16x32_bf16(af[mt], bfr[nt], acc[mt][nt], 0, 0, 0);
  }
  const float* bias = (sel == 0) ? bq : (sel == 1) ? bk : bv;
  u16* dst = (sel == 0) ? qb : (sel == 1) ? kb : vb;
#pragma unroll
  for (int mt = 0; mt < 4; mt++) {
#pragma unroll
    for (int nt = 0; nt < 4; nt++) {
      int lc = or0 + wc + nt * 16 + lm;
      float bb = bias[lc];
#pragma unroll
      for (int r = 0; r < 4; r++) {
        int row = m0 + wr + mt * 16 + lq * 4 + r;   // C/D: row=quad*4+reg, col=lane&15
        dst[(size_t)row * HID_ + lc] = f2b(acc[mt][nt][r] + bb);
      }
    }
  }
}

// ---------------- global max of k features per (b,h) ----------------
__global__ __launch_bounds__(512) void k_kmax(
    const u16* __restrict__ kb, const u16* __restrict__ projb, unsigned* __restrict__ mbuf) {
  __shared__ u16 Pl[NBP_][72];
  __shared__ u16 Kl[64][72];
  const int bh = blockIdx.y;
  const int b = bh / H_, h = bh - b * H_;
  const int n0 = blockIdx.x * 256;
  const int t = threadIdx.x, lane = t & 63, wv = t >> 6;
  const int lm = lane & 15, lq = lane >> 4;
  for (int c = t; c < NBP_ * 8; c += 512) {
    int j = c >> 3, off = (c & 7) * 8;
    *(uint4*)&Pl[j][off] = *(const uint4*)(projb + j * 64 + off);
  }
  const size_t base = ((size_t)b * N_) * HID_ + h * DH_;
  const int mt = wv >> 1, ct0 = (wv & 1) * 9;
  float mx = -3.0e38f;
  for (int s = 0; s < 4; s++) {
    __syncthreads();
    {
      int r = t >> 3, off = (t & 7) * 8;
      *(uint4*)&Kl[r][off] = *(const uint4*)(kb + base + (size_t)(n0 + s * 64 + r) * HID_ + off);
    }
    __syncthreads();
    short8 af0 = *(const short8*)&Kl[mt * 16 + lm][lq * 8];
    short8 af1 = *(const short8*)&Kl[mt * 16 + lm][32 + lq * 8];
#pragma unroll
    for (int ci = 0; ci < 9; ci++) {
      int ct = ct0 + ci;
      short8 bf0 = *(const short8*)&Pl[ct * 16 + lm][lq * 8];
      short8 bf1 = *(const short8*)&Pl[ct * 16 + lm][32 + lq * 8];
      floatx4 a = __builtin_amdgcn_mfma_f32_16x16x32_bf16(af0, bf0, (floatx4){0.f,0.f,0.f,0.f}, 0,0,0);
      a = __builtin_amdgcn_mfma_f32_16x16x32_bf16(af1, bf1, a, 0, 0, 0);
      int j = ct * 16 + lm;
      if (j < NB_) {
#pragma unroll
        for (int r = 0; r < 4; r++) mx = fmaxf(mx, a[r]);
      }
    }
  }
#pragma unroll
  for (int o = 1; o < 64; o <<= 1) mx = fmaxf(mx, __shfl_xor(mx, o));
  if (lane == 0) atomicMax(&mbuf[bh], fmap(mx));
}

// ---------------- kp features -> ctx^T [64xNBP] and k_sum ----------------
__global__ __launch_bounds__(512) void k_ctx(
    const u16* __restrict__ kb, const u16* __restrict__ vbuf, const u16* __restrict__ projb,
    const unsigned* __restrict__ mbuf, float* __restrict__ ctxT, float* __restrict__ ksum) {
  __shared__ u16 Pl[NBP_][72];
  __shared__ u16 Kl[64][72];
  __shared__ u16 vT[64][72];      // v transposed: [dv][n], pad 72 for align+banks
  __shared__ u16 kpT[NBP_][72];   // kp transposed: [j][n]
  __shared__ float ksloc[NBP_];
  const int bh = blockIdx.y;
  const int b = bh / H_, h = bh - b * H_;
  const int n0 = blockIdx.x * 256;
  const int t = threadIdx.x, lane = t & 63, wv = t >> 6;
  const int lm = lane & 15, lq = lane >> 4;
  for (int c = t; c < NBP_ * 8; c += 512) {
    int j = c >> 3, off = (c & 7) * 8;
    *(uint4*)&Pl[j][off] = *(const uint4*)(projb + j * 64 + off);
  }
  for (int c = t; c < NBP_; c += 512) ksloc[c] = 0.f;
  const float m = funmap(mbuf[bh]);
  const float ratio = 0.06131393f;  // 266^-0.5
  const size_t base = ((size_t)b * N_) * HID_ + h * DH_;
  const int mt = wv >> 1, ct0 = (wv & 1) * 9;
  floatx4 accc[9];
#pragma unroll
  for (int i = 0; i < 9; i++) accc[i] = (floatx4){0.f, 0.f, 0.f, 0.f};

  for (int s = 0; s < 4; s++) {
    __syncthreads();
    {
      int r = t >> 3, off = (t & 7) * 8;
      *(uint4*)&Kl[r][off] = *(const uint4*)(kb + base + (size_t)(n0 + s * 64 + r) * HID_ + off);
      uint4 vvv = *(const uint4*)(vbuf + base + (size_t)(n0 + s * 64 + r) * HID_ + off);
      const u16* pv = (const u16*)&vvv;
#pragma unroll
      for (int i = 0; i < 8; i++) vT[off + i][r] = pv[i];
    }
    __syncthreads();
    short8 af0 = *(const short8*)&Kl[mt * 16 + lm][lq * 8];
    short8 af1 = *(const short8*)&Kl[mt * 16 + lm][32 + lq * 8];
    // diag = 0.5*dn^2*sum(k^2) per row; computed from A-frags, row held at lane lm
    float rs = 0.f;
#pragma unroll
    for (int i = 0; i < 8; i++) { float f = b2f(((const u16*)&af0)[i]); rs += f * f; }
#pragma unroll
    for (int i = 0; i < 8; i++) { float f = b2f(((const u16*)&af1)[i]); rs += f * f; }
    rs += __shfl_xor(rs, 16);
    rs += __shfl_xor(rs, 32);
    float dg[4];
#pragma unroll
    for (int r = 0; r < 4; r++) dg[r] = 0.0625f * __shfl(rs, lq * 4 + r);  // 0.5*dn^2 = 1/16
#pragma unroll
    for (int ci = 0; ci < 9; ci++) {
      int ct = ct0 + ci;
      short8 bf0 = *(const short8*)&Pl[ct * 16 + lm][lq * 8];
      short8 bf1 = *(const short8*)&Pl[ct * 16 + lm][32 + lq * 8];
      floatx4 a = __builtin_amdgcn_mfma_f32_16x16x32_bf16(af0, bf0, (floatx4){0.f,0.f,0.f,0.f}, 0,0,0);
      a = __builtin_amdgcn_mfma_f32_16x16x32_bf16(af1, bf1, a, 0, 0, 0);
      int j = ct * 16 + lm;
      float kss = 0.f;
#pragma unroll
      for (int r = 0; r < 4; r++) {
        float val = (j < NB_) ? ratio * (__expf(a[r] - dg[r] - m) + EPS_) : 0.f;
        kss += val;
        kpT[j][mt * 16 + lq * 4 + r] = f2b(val);
      }
      kss += __shfl_xor(kss, 16);
      kss += __shfl_xor(kss, 32);
      if (lq == 0) atomicAdd(&ksloc[j], kss);
    }
    __syncthreads();
    // ctx^T[dv][j] += sum_n v[n][dv]*kp[n][j]:  A=vT (m=dv,k=n), B=kpT (k=n,n'=j)
    short8 av0 = *(const short8*)&vT[mt * 16 + lm][lq * 8];
    short8 av1 = *(const short8*)&vT[mt * 16 + lm][32 + lq * 8];
#pragma unroll
    for (int ci = 0; ci < 9; ci++) {
      int ct = ct0 + ci;
      short8 bk0 = *(const short8*)&kpT[ct * 16 + lm][lq * 8];
      short8 bk1 = *(const short8*)&kpT[ct * 16 + lm][32 + lq * 8];
      accc[ci] = __builtin_amdgcn_mfma_f32_16x16x32_bf16(av0, bk0, accc[ci], 0, 0, 0);
      accc[ci] = __builtin_amdgcn_mfma_f32_16x16x32_bf16(av1, bk1, accc[ci], 0, 0, 0);
    }
  }
  __syncthreads();
  for (int c = t; c < NBP_; c += 512) atomicAdd(&ksum[(size_t)bh * NBP_ + c], ksloc[c]);
#pragma unroll
  for (int ci = 0; ci < 9; ci++) {
    int j = (ct0 + ci) * 16 + lm;
#pragma unroll
    for (int r = 0; r < 4; r++) {
      int dv = mt * 16 + lq * 4 + r;
      atomicAdd(&ctxT[((size_t)bh * 64 + dv) * NBP_ + j], accc[ci][r]);
    }
  }
}

// ---------------- qp features -> out = (qp @ ctx) * d_inv ----------------
__global__ __launch_bounds__(512) void k_out(
    const u16* __restrict__ qb, const u16* __restrict__ projb,
    const float* __restrict__ ctxT, const float* __restrict__ ksum,
    float* __restrict__ outp) {
  __shared__ u16 Pl[NBP_][72];
  __shared__ u16 Ql[64][72];
  __shared__ u16 qpl[64][296];   // qp in [n][j] (A-operand layout), stride 296: aligned + 2-way banks
  __shared__ u16 cxl[64][296];   // ctx^T in [dv][j] (B-operand layout)
  __shared__ float ksl[NBP_];
  __shared__ unsigned rmx[64];
  __shared__ float dsum[64];
  const int bh = blockIdx.y;
  const int b = bh / H_, h = bh - b * H_;
  const int n0 = blockIdx.x * 256;
  const int t = threadIdx.x, lane = t & 63, wv = t >> 6;
  const int lm = lane & 15, lq = lane >> 4;
  for (int c = t; c < NBP_ * 8; c += 512) {
    int j = c >> 3, off = (c & 7) * 8;
    *(uint4*)&Pl[j][off] = *(const uint4*)(projb + j * 64 + off);
  }
  for (int c = t; c < 64 * NBP_; c += 512) {
    int dv = c / NBP_, j = c - dv * NBP_;
    cxl[dv][j] = f2b(ctxT[(size_t)bh * 64 * NBP_ + c]);
  }
  for (int c = t; c < NBP_; c += 512) ksl[c] = ksum[(size_t)bh * NBP_ + c];
  const float ratio = 0.06131393f;
  const size_t base = ((size_t)b * N_) * HID_ + h * DH_;
  const int mt = wv >> 1, ct0 = (wv & 1) * 9;

  for (int s = 0; s < 4; s++) {
    __syncthreads();
    {
      int r = t >> 3, off = (t & 7) * 8;
      *(uint4*)&Ql[r][off] = *(const uint4*)(qb + base + (size_t)(n0 + s * 64 + r) * HID_ + off);
    }
    if (t < 64) { rmx[t] = 0u; dsum[t] = 0.f; }
    __syncthreads();
    short8 af0 = *(const short8*)&Ql[mt * 16 + lm][lq * 8];
    short8 af1 = *(const short8*)&Ql[mt * 16 + lm][32 + lq * 8];
    float rs = 0.f;
#pragma unroll
    for (int i = 0; i < 8; i++) { float f = b2f(((const u16*)&af0)[i]); rs += f * f; }
#pragma unroll
    for (int i = 0; i < 8; i++) { float f = b2f(((const u16*)&af1)[i]); rs += f * f; }
    rs += __shfl_xor(rs, 16);
    rs += __shfl_xor(rs, 32);
    float dg[4];
#pragma unroll
    for (int r = 0; r < 4; r++) dg[r] = 0.0625f * __shfl(rs, lq * 4 + r);
    floatx4 dd[9];
    float rm[4] = {-3e38f, -3e38f, -3e38f, -3e38f};
#pragma unroll
    for (int ci = 0; ci < 9; ci++) {
      int ct = ct0 + ci;
      short8 bf0 = *(const short8*)&Pl[ct * 16 + lm][lq * 8];
      short8 bf1 = *(const short8*)&Pl[ct * 16 + lm][32 + lq * 8];
      floatx4 a = __builtin_amdgcn_mfma_f32_16x16x32_bf16(af0, bf0, (floatx4){0.f,0.f,0.f,0.f}, 0,0,0);
      a = __builtin_amdgcn_mfma_f32_16x16x32_bf16(af1, bf1, a, 0, 0, 0);
      dd[ci] = a;
      int j = ct * 16 + lm;
      if (j < NB_) {
#pragma unroll
        for (int r = 0; r < 4; r++) rm[r] = fmaxf(rm[r], a[r]);
      }
    }
#pragma unroll
    for (int o = 1; o < 16; o <<= 1) {
#pragma unroll
      for (int r = 0; r < 4; r++) rm[r] = fmaxf(rm[r], __shfl_xor(rm[r], o));
    }
    if (lm == 0) {
#pragma unroll
      for (int r = 0; r < 4; r++) atomicMax(&rmx[mt * 16 + lq * 4 + r], fmap(rm[r]));
    }
    __syncthreads();
    float dpart[4] = {0.f, 0.f, 0.f, 0.f};
    float mrow[4];
#pragma unroll
    for (int r = 0; r < 4; r++) mrow[r] = funmap(rmx[mt * 16 + lq * 4 + r]);
#pragma unroll
    for (int ci = 0; ci < 9; ci++) {
      int ct = ct0 + ci;
      int j = ct * 16 + lm;
      float ks = ksl[j];
#pragma unroll
      for (int r = 0; r < 4; r++) {
        float qpv = (j < NB_) ? ratio * (__expf(dd[ci][r] - dg[r] - mrow[r]) + EPS_) : 0.f;
        qpl[mt * 16 + lq * 4 + r][j] = f2b(qpv);
        dpart[r] += qpv * ks;
      }
    }
#pragma unroll
    for (int o = 1; o < 16; o <<= 1) {
#pragma unroll
      for (int r = 0; r < 4; r++) dpart[r] += __shfl_xor(dpart[r], o);
    }
    if (lm == 0) {
#pragma unroll
      for (int r = 0; r < 4; r++) atomicAdd(&dsum[mt * 16 + lq * 4 + r], dpart[r]);
    }
    __syncthreads();
    // out tile: D[n][dv] = sum_j qp[n][j]*ctx[j][dv]; wave: n-tile=mt, dv-tiles dt0..dt0+1
    const int dt0 = (wv & 1) * 2;
    floatx4 ao[2];
    ao[0] = (floatx4){0.f, 0.f, 0.f, 0.f};
    ao[1] = (floatx4){0.f, 0.f, 0.f, 0.f};
#pragma unroll
    for (int ks_ = 0; ks_ < 9; ks_++) {
      short8 aq = *(const short8*)&qpl[mt * 16 + lm][ks_ * 32 + lq * 8];
#pragma unroll
      for (int dt = 0; dt < 2; dt++) {
        short8 bc = *(const short8*)&cxl[(dt0 + dt) * 16 + lm][ks_ * 32 + lq * 8];
        ao[dt] = __builtin_amdgcn_mfma_f32_16x16x32_bf16(aq, bc, ao[dt], 0, 0, 0);
      }
    }
#pragma unroll
    for (int dt = 0; dt < 2; dt++) {
#pragma unroll
      for (int r = 0; r < 4; r++) {
        int nloc = mt * 16 + lq * 4 + r;
        float di = 1.f / dsum[nloc];
        int n = n0 + s * 64 + nloc;
        int dv = (dt0 + dt) * 16 + lm;
        outp[((size_t)b * N_ + n) * HID_ + h * DH_ + dv] = ao[dt][r] * di;
      }
    }
  }
}

extern "C" void kernel_launch(void* const* d_in, const int* in_sizes, int n_in,
                              void* d_out, int out_size, void* d_ws, size_t ws_size,
                              hipStream_t stream) {
  (void)in_sizes; (void)n_in; (void)out_size; (void)ws_size;
  const float* hs   = (const float*)d_in[0];
  const float* Wq   = (const float*)d_in[1];
  const float* bq   = (const float*)d_in[2];
  const float* Wk   = (const float*)d_in[3];
  const float* bk   = (const float*)d_in[4];
  const float* Wv   = (const float*)d_in[5];
  const float* bv   = (const float*)d_in[6];
  const float* proj = (const float*)d_in[7];

  char* w = (char*)d_ws;
  u16* hsb   = (u16*)w;  w += (size_t)16384 * 768 * 2;
  u16* wb3   = (u16*)w;  w += (size_t)3 * 768 * 768 * 2;
  u16* projb = (u16*)w;  w += (size_t)NBP_ * 64 * 2;
  u16* qb    = (u16*)w;  w += (size_t)16384 * 768 * 2;
  u16* kb    = (u16*)w;  w += (size_t)16384 * 768 * 2;
  u16* vb    = (u16*)w;  w += (size_t)16384 * 768 * 2;
  float* ctxT = (float*)w; w += (size_t)48 * 64 * NBP_ * 4;
  float* ksum = (float*)w; w += (size_t)48 * NBP_ * 4;
  unsigned* mbuf = (unsigned*)w;

  hipLaunchKernelGGL(k_convert, dim3(2048), dim3(256), 0, stream, hs, hsb, 16384 * 768);
  hipLaunchKernelGGL(k_convert, dim3(576), dim3(256), 0, stream, Wq, wb3, 768 * 768);
  hipLaunchKernelGGL(k_convert, dim3(576), dim3(256), 0, stream, Wk, wb3 + 768 * 768, 768 * 768);
  hipLaunchKernelGGL(k_convert, dim3(576), dim3(256), 0, stream, Wv, wb3 + 2 * 768 * 768, 768 * 768);
  hipLaunchKernelGGL(k_prep_proj, dim3(72), dim3(256), 0, stream, proj, projb);
  int nz = 48 * 64 * NBP_ + 48 * NBP_;  // ctxT + ksum are contiguous
  hipLaunchKernelGGL(k_init, dim3((nz + 255) / 256), dim3(256), 0, stream, ctxT, mbuf, nz);
  hipLaunchKernelGGL(k_qkv, dim3(128, 18), dim3(256), 0, stream, hsb, wb3, bq, bk, bv, qb, kb, vb);
  hipLaunchKernelGGL(k_kmax, dim3(16, 48), dim3(512), 0, stream, kb, projb, mbuf);
  hipLaunchKernelGGL(k_ctx, dim3(16, 48), dim3(512), 0, stream, kb, vb, projb, mbuf, ctxT, ksum);
  hipLaunchKernelGGL(k_out, dim3(16, 48), dim3(512), 0, stream, qb, projb, ctxT, ksum, (float*)d_out);
}